// Round 2
// baseline (233.641 us; speedup 1.0000x reference)
//
#include <hip/hip_runtime.h>
#include <math.h>

#define N_NODES 50000
#define N_EDGES 800000
#define CH 128
#define CAP 48   // slots per node; deg ~ Poisson(16), P(deg>=48) ~ 1e-10
#define SCAT_BLOCKS ((N_EDGES + 255) / 256)   // 3125
#define GEMM_BLOCKS ((N_NODES + 63) / 64)     // 782
#define TOTAL_BLOCKS (SCAT_BLOCKS + GEMM_BLOCKS)  // 3907

typedef __attribute__((ext_vector_type(8))) short short8;
typedef __attribute__((ext_vector_type(4))) float f32x4;
union FragU { uint4 u; short8 s; };

// RNE-pack two fp32 into (lo,hi) bf16 halves of a uint.
__device__ __forceinline__ unsigned pack_bf16(float a, float b) {
    unsigned ua = __float_as_uint(a);
    unsigned ub = __float_as_uint(b);
    ua += 0x7FFFu + ((ua >> 16) & 1u);
    ub += 0x7FFFu + ((ub >> 16) & 1u);
    return (ua >> 16) | (ub & 0xFFFF0000u);
}

// ---------------------------------------------------------------------------
// prep_pack: swizzle W_l,W_r (fp32 [out][in]) into MFMA B-fragment-ordered
// bf16 (layout proven round 7). Also zeroes counts (folds the memset dispatch).
__global__ __launch_bounds__(256) void prep_pack_kernel(
    const float* __restrict__ W_l, const float* __restrict__ W_r,
    uint4* __restrict__ Wf4, int* __restrict__ counts)
{
    int tid = blockIdx.x * 256 + threadIdx.x;   // grid 64 blocks -> 16384 threads
    if (tid < 2 * 8 * 4 * 64) {
        int lane  = tid & 63;
        int chunk = (tid >> 6) & 3;
        int tile  = (tid >> 8) & 7;
        int mat   = tid >> 11;
        const float* W = mat ? W_r : W_l;
        int n  = tile * 16 + (lane & 15);
        int k0 = chunk * 32 + (lane >> 4) * 8;
        const float* wp = W + n * CH + k0;
        float4 a = *(const float4*)wp;
        float4 b = *(const float4*)(wp + 4);
        uint4 p;
        p.x = pack_bf16(a.x, a.y);
        p.y = pack_bf16(a.z, a.w);
        p.z = pack_bf16(b.x, b.y);
        p.w = pack_bf16(b.z, b.w);
        Wf4[tid] = p;
    }
    for (int i = tid; i < N_NODES; i += 64 * 256) counts[i] = 0;
}

// ---------------------------------------------------------------------------
// Fused scatter + GEMM. GEMM blocks are STRIPED 1-in-5 through the grid
// (blocks dispatch in index order; striping keeps ~1 compute-dense GEMM block
// co-resident with ~3 latency-bound scatter blocks on every CU for the whole
// kernel, instead of a GEMM-only tail after the scatter drains).
__global__ __launch_bounds__(256) void fused_scatter_gemm_kernel(
    const int* __restrict__ src, const int* __restrict__ dst,
    const float* __restrict__ env,
    int* __restrict__ counts, unsigned* __restrict__ recs,
    const float* __restrict__ q, const uint4* __restrict__ Wf4,
    unsigned short* __restrict__ g_l16, float* __restrict__ g_r)
{
    const int b = blockIdx.x;
    const bool is_gemm = ((b % 5) == 0) && (b / 5 < GEMM_BLOCKS);
    if (!is_gemm) {
        // ---- scatter: rec = src(low16) | bf16(env+1e-7)(high16), 4B nt store
        const int s = b - b / 5 - 1;           // b%5 != 0 here
        int i = s * 256 + threadIdx.x;
        if (i < N_EDGES) {
            int d = dst[i];
            int rank = atomicAdd(&counts[d], 1);
            if (rank < CAP) {
                unsigned ev = __float_as_uint(env[i] + 1e-7f);
                ev += 0x7FFFu + ((ev >> 16) & 1u);     // RNE to bf16
                unsigned rec = (unsigned)src[i] | (ev & 0xFFFF0000u);
                // nt: written once, read by next kernel; avoid partial-line
                // writeback churn from 8 non-coherent L2s.
                __builtin_nontemporal_store(rec, &recs[d * CAP + rank]);
            }
        }
    } else {
        // ---- MFMA GEMM: g_l(bf16) = q@W_l^T, g_r(fp32) = q@W_r^T
        // layouts [m89/m91]: A/B lane idx = lane&15; C/D col=lane&15,
        // row=(lane>>4)*4+reg.
        const int g    = b / 5;
        const int wv   = threadIdx.x >> 6;
        const int lane = threadIdx.x & 63;
        const int m    = lane & 15;
        const int quad = lane >> 4;
        const int row0 = g * 64 + wv * 16;

        int arow = row0 + m;
        if (arow >= N_NODES) arow = N_NODES - 1;   // clamp (stores guarded)
        const float* qr = q + (size_t)arow * CH + quad * 8;

        FragU A[4];
        #pragma unroll
        for (int c = 0; c < 4; ++c) {
            float4 x = *(const float4*)(qr + c * 32);
            float4 y = *(const float4*)(qr + c * 32 + 4);
            A[c].u.x = pack_bf16(x.x, x.y);
            A[c].u.y = pack_bf16(x.z, x.w);
            A[c].u.z = pack_bf16(y.x, y.y);
            A[c].u.w = pack_bf16(y.z, y.w);
        }

        for (int mat = 0; mat < 2; ++mat) {
            for (int tile = 0; tile < 8; ++tile) {
                f32x4 acc = {0.f, 0.f, 0.f, 0.f};
                const uint4* bp = Wf4 + (size_t)((mat * 8 + tile) * 4) * 64 + lane;
                #pragma unroll
                for (int c = 0; c < 4; ++c) {
                    FragU B; B.u = bp[c * 64];
                    acc = __builtin_amdgcn_mfma_f32_16x16x32_bf16(A[c].s, B.s, acc, 0, 0, 0);
                }
                int col = tile * 16 + m;
                #pragma unroll
                for (int r = 0; r < 4; ++r) {
                    int rowg = row0 + quad * 4 + r;
                    if (rowg < N_NODES) {
                        if (mat == 0) {
                            unsigned u = __float_as_uint(acc[r]);
                            u += 0x7FFFu + ((u >> 16) & 1u);
                            g_l16[(size_t)rowg * CH + col] = (unsigned short)(u >> 16);
                        } else {
                            __builtin_nontemporal_store(acc[r], &g_r[(size_t)rowg * CH + col]);
                        }
                    }
                }
            }
        }
    }
}

// ---------------------------------------------------------------------------
// One wave per node, quarter-wave (16 lanes x 8 ch) per edge, 4 edges/group.
// V2: ALL <=48 records of the bucket are preloaded in ONE coalesced 4B/lane
// load; per-group records come from a register via one shfl. This removes
// the per-iteration rec-load -> gather dependent chain, so the g_l gathers can
// be pipelined depth-3 (covers ~600cy L3 gather latency with ~200cy/group
// compute).
__global__ __launch_bounds__(256) void node_attn_kernel(
    const uint4* __restrict__ g_lb4, const float* __restrict__ g_r,
    const float* __restrict__ attn_w,
    const unsigned* __restrict__ recs, const int* __restrict__ counts,
    float* __restrict__ out)
{
    int gid = blockIdx.x * blockDim.x + threadIdx.x;
    int wid = gid >> 6;
    if (wid >= N_NODES) return;
    const int lane = threadIdx.x & 63;
    const int q4 = lane >> 4;    // quarter 0..3: which edge of the group of 4
    const int sl = lane & 15;    // sub-lane: channels sl*8 .. sl*8+7

    int cnt = counts[wid];
    if (cnt > CAP) cnt = CAP;

    float gr[8], aw[8];
    {
        const f32x4* grp = (const f32x4*)(g_r + (size_t)wid * CH + sl * 8);
        f32x4 a = __builtin_nontemporal_load(grp);
        f32x4 b = __builtin_nontemporal_load(grp + 1);
        gr[0] = a.x; gr[1] = a.y; gr[2] = a.z; gr[3] = a.w;
        gr[4] = b.x; gr[5] = b.y; gr[6] = b.z; gr[7] = b.w;
        const float4* awp = (const float4*)(attn_w + sl * 8);
        float4 c = awp[0], d = awp[1];
        aw[0] = c.x; aw[1] = c.y; aw[2] = c.z; aw[3] = c.w;
        aw[4] = d.x; aw[5] = d.y; aw[6] = d.z; aw[7] = d.w;
    }

    float l = 0.0f;
    float acc[8] = {0.f, 0.f, 0.f, 0.f, 0.f, 0.f, 0.f, 0.f};

    if (cnt > 0) {
        const int clampi = cnt - 1;
        // whole bucket in one coalesced load (lanes >= cnt clamp to last slot)
        unsigned rcl = recs[wid * CAP + min(lane, clampi)];
        const int G = (cnt + 3) >> 2;   // groups of 4 edges

        #define REC_OF(jg, rv) { int e_ = (jg) * 4 + q4; if (e_ > clampi) e_ = clampi; \
                                 rv = __shfl(rcl, e_, 64); }

        unsigned r0, r1, r2, r3;
        uint4 gA, gB, gC, gD;
        REC_OF(0, r0); gA = g_lb4[(size_t)(r0 & 0xFFFFu) * (CH / 8) + sl];
        r1 = r0; r2 = r0; gB = gA; gC = gA;
        if (G > 1) { REC_OF(1, r1); gB = g_lb4[(size_t)(r1 & 0xFFFFu) * (CH / 8) + sl]; }
        if (G > 2) { REC_OF(2, r2); gC = g_lb4[(size_t)(r2 & 0xFFFFu) * (CH / 8) + sl]; }

        for (int j = 0; j < G; ++j) {
            r3 = r0; gD = gA;                 // init so tail rotation is defined
            if (j + 3 < G) {                  // wave-uniform branch
                REC_OF(j + 3, r3);
                gD = g_lb4[(size_t)(r3 & 0xFFFFu) * (CH / 8) + sl];
            }

            bool active = (j * 4 + q4) < cnt;
            float ev = __uint_as_float(r0 & 0xFFFF0000u);

            float gl[8];
            gl[0] = __uint_as_float(gA.x << 16);
            gl[1] = __uint_as_float(gA.x & 0xFFFF0000u);
            gl[2] = __uint_as_float(gA.y << 16);
            gl[3] = __uint_as_float(gA.y & 0xFFFF0000u);
            gl[4] = __uint_as_float(gA.z << 16);
            gl[5] = __uint_as_float(gA.z & 0xFFFF0000u);
            gl[6] = __uint_as_float(gA.w << 16);
            gl[7] = __uint_as_float(gA.w & 0xFFFF0000u);

            float p = 0.0f;
            #pragma unroll
            for (int c = 0; c < 8; ++c) {
                float h = gl[c] + gr[c];
                float sg = __builtin_amdgcn_rcpf(1.0f + __expf(-h));  // sigmoid
                p = fmaf(h * aw[c], sg, p);                            // silu*aw
            }
            p += __shfl_xor(p, 1, 64);
            p += __shfl_xor(p, 2, 64);
            p += __shfl_xor(p, 4, 64);
            p += __shfl_xor(p, 8, 64);

            float w = __expf(p) * (active ? ev : 0.0f);  // = exp(p+log(env))
            l += w;
            #pragma unroll
            for (int c = 0; c < 8; ++c) acc[c] = fmaf(w, gl[c], acc[c]);

            r0 = r1; gA = gB; r1 = r2; gB = gC; r2 = r3; gC = gD;
        }
        #undef REC_OF
    }

    #pragma unroll
    for (int o = 16; o <= 32; o <<= 1) {
        l += __shfl_xor(l, o, 64);
        #pragma unroll
        for (int c = 0; c < 8; ++c) acc[c] += __shfl_xor(acc[c], o, 64);
    }

    if (q4 == 0) {
        float inv = (l > 0.0f) ? __builtin_amdgcn_rcpf(l) : 0.0f;
        f32x4 o0 = {acc[0] * inv, acc[1] * inv, acc[2] * inv, acc[3] * inv};
        f32x4 o1 = {acc[4] * inv, acc[5] * inv, acc[6] * inv, acc[7] * inv};
        f32x4* op = (f32x4*)(out + (size_t)wid * CH + sl * 8);
        __builtin_nontemporal_store(o0, op);
        __builtin_nontemporal_store(o1, op + 1);
    }
}

// ---------------------------------------------------------------------------
extern "C" void kernel_launch(void* const* d_in, const int* in_sizes, int n_in,
                              void* d_out, int out_size, void* d_ws, size_t ws_size,
                              hipStream_t stream)
{
    const float* q      = (const float*)d_in[0];
    // d_in[1]=k, d_in[2]=v : unused (matches reference)
    const float* env    = (const float*)d_in[3];
    const float* W_l    = (const float*)d_in[4];
    const float* W_r    = (const float*)d_in[5];
    const float* attn_w = (const float*)d_in[6];
    const int*   eidx   = (const int*)d_in[7];
    const int* src = eidx;
    const int* dst = eidx + N_EDGES;
    float* out = (float*)d_out;

    float* ws    = (float*)d_ws;
    unsigned* g_lb = (unsigned*)ws;                      // N*CH/2 uints (bf16 pairs)
    float* g_r   = (float*)(g_lb + (size_t)N_NODES * (CH / 2));  // N*CH fp32
    uint4* Wf4   = (uint4*)(g_r + (size_t)N_NODES * CH); // 4096 uint4 = 64 KB
    unsigned* recs = (unsigned*)(Wf4 + 4096);            // N*CAP 4B records (9.6 MB)
    int* counts  = (int*)(recs + (size_t)N_NODES * CAP); // N

    prep_pack_kernel<<<64, 256, 0, stream>>>(W_l, W_r, Wf4, counts);

    fused_scatter_gemm_kernel<<<TOTAL_BLOCKS, 256, 0, stream>>>(
        src, dst, env, counts, recs, q, Wf4, (unsigned short*)g_lb, g_r);

    int node_wave_blocks = (N_NODES * 64 + 255) / 256;
    node_attn_kernel<<<node_wave_blocks, 256, 0, stream>>>(
        (const uint4*)g_lb, g_r, attn_w, recs, counts, out);
}

// Round 3
// 229.245 us; speedup vs baseline: 1.0192x; 1.0192x over previous
//
#include <hip/hip_runtime.h>
#include <math.h>

#define N_NODES 50000
#define N_EDGES 800000
#define CH 128
#define CAP 48   // slots per node; deg ~ Poisson(16), P(deg>=48) ~ 1e-10
#define SCAT_BLOCKS ((N_EDGES + 255) / 256)   // 3125
#define GEMM_BLOCKS ((N_NODES + 63) / 64)     // 782
#define TOTAL_BLOCKS (SCAT_BLOCKS + GEMM_BLOCKS)  // 3907

typedef __attribute__((ext_vector_type(8))) short short8;
typedef __attribute__((ext_vector_type(4))) float f32x4;
union FragU { uint4 u; short8 s; };

// RNE-pack two fp32 into (lo,hi) bf16 halves of a uint.
__device__ __forceinline__ unsigned pack_bf16(float a, float b) {
    unsigned ua = __float_as_uint(a);
    unsigned ub = __float_as_uint(b);
    ua += 0x7FFFu + ((ua >> 16) & 1u);
    ub += 0x7FFFu + ((ub >> 16) & 1u);
    return (ua >> 16) | (ub & 0xFFFF0000u);
}

// ---------------------------------------------------------------------------
// prep_pack: swizzle W_l,W_r (fp32 [out][in]) into MFMA B-fragment-ordered
// bf16 (layout proven round 7). Also zeroes counts (folds the memset dispatch).
__global__ __launch_bounds__(256) void prep_pack_kernel(
    const float* __restrict__ W_l, const float* __restrict__ W_r,
    uint4* __restrict__ Wf4, int* __restrict__ counts)
{
    int tid = blockIdx.x * 256 + threadIdx.x;   // grid 64 blocks -> 16384 threads
    if (tid < 2 * 8 * 4 * 64) {
        int lane  = tid & 63;
        int chunk = (tid >> 6) & 3;
        int tile  = (tid >> 8) & 7;
        int mat   = tid >> 11;
        const float* W = mat ? W_r : W_l;
        int n  = tile * 16 + (lane & 15);
        int k0 = chunk * 32 + (lane >> 4) * 8;
        const float* wp = W + n * CH + k0;
        float4 a = *(const float4*)wp;
        float4 b = *(const float4*)(wp + 4);
        uint4 p;
        p.x = pack_bf16(a.x, a.y);
        p.y = pack_bf16(a.z, a.w);
        p.z = pack_bf16(b.x, b.y);
        p.w = pack_bf16(b.z, b.w);
        Wf4[tid] = p;
    }
    for (int i = tid; i < N_NODES; i += 64 * 256) counts[i] = 0;
}

// ---------------------------------------------------------------------------
// Fused scatter + GEMM. GEMM blocks are STRIPED 1-in-5 through the grid
// (blocks dispatch in index order; striping keeps ~1 compute-dense GEMM block
// co-resident with ~3 latency-bound scatter blocks on every CU for the whole
// kernel, instead of a GEMM-only tail after the scatter drains).
// NOTE (round-2 post-mortem): NO nontemporal stores here. recs/g_r/g_l are
// producer->consumer intermediates that fit L3 (9.6/25.6/12.8 MB of 256 MB);
// nt stores forced them to HBM (+11 MB WRITE_SIZE) and made the consumer
// kernel's reads miss L3. Plain cached stores are strictly better.
__global__ __launch_bounds__(256) void fused_scatter_gemm_kernel(
    const int* __restrict__ src, const int* __restrict__ dst,
    const float* __restrict__ env,
    int* __restrict__ counts, unsigned* __restrict__ recs,
    const float* __restrict__ q, const uint4* __restrict__ Wf4,
    unsigned short* __restrict__ g_l16, float* __restrict__ g_r)
{
    const int b = blockIdx.x;
    const bool is_gemm = ((b % 5) == 0) && (b / 5 < GEMM_BLOCKS);
    if (!is_gemm) {
        // ---- scatter: rec = src(low16) | bf16(env+1e-7)(high16), 4B store
        const int s = b - b / 5 - 1;           // b%5 != 0 here
        int i = s * 256 + threadIdx.x;
        if (i < N_EDGES) {
            int d = dst[i];
            int rank = atomicAdd(&counts[d], 1);
            if (rank < CAP) {
                unsigned ev = __float_as_uint(env[i] + 1e-7f);
                ev += 0x7FFFu + ((ev >> 16) & 1u);     // RNE to bf16
                recs[d * CAP + rank] = (unsigned)src[i] | (ev & 0xFFFF0000u);
            }
        }
    } else {
        // ---- MFMA GEMM: g_l(bf16) = q@W_l^T, g_r(fp32) = q@W_r^T
        // layouts [m89/m91]: A/B lane idx = lane&15; C/D col=lane&15,
        // row=(lane>>4)*4+reg.
        const int g    = b / 5;
        const int wv   = threadIdx.x >> 6;
        const int lane = threadIdx.x & 63;
        const int m    = lane & 15;
        const int quad = lane >> 4;
        const int row0 = g * 64 + wv * 16;

        int arow = row0 + m;
        if (arow >= N_NODES) arow = N_NODES - 1;   // clamp (stores guarded)
        const float* qr = q + (size_t)arow * CH + quad * 8;

        FragU A[4];
        #pragma unroll
        for (int c = 0; c < 4; ++c) {
            float4 x = *(const float4*)(qr + c * 32);
            float4 y = *(const float4*)(qr + c * 32 + 4);
            A[c].u.x = pack_bf16(x.x, x.y);
            A[c].u.y = pack_bf16(x.z, x.w);
            A[c].u.z = pack_bf16(y.x, y.y);
            A[c].u.w = pack_bf16(y.z, y.w);
        }

        for (int mat = 0; mat < 2; ++mat) {
            for (int tile = 0; tile < 8; ++tile) {
                f32x4 acc = {0.f, 0.f, 0.f, 0.f};
                const uint4* bp = Wf4 + (size_t)((mat * 8 + tile) * 4) * 64 + lane;
                #pragma unroll
                for (int c = 0; c < 4; ++c) {
                    FragU B; B.u = bp[c * 64];
                    acc = __builtin_amdgcn_mfma_f32_16x16x32_bf16(A[c].s, B.s, acc, 0, 0, 0);
                }
                int col = tile * 16 + m;
                #pragma unroll
                for (int r = 0; r < 4; ++r) {
                    int rowg = row0 + quad * 4 + r;
                    if (rowg < N_NODES) {
                        if (mat == 0) {
                            unsigned u = __float_as_uint(acc[r]);
                            u += 0x7FFFu + ((u >> 16) & 1u);
                            g_l16[(size_t)rowg * CH + col] = (unsigned short)(u >> 16);
                        } else {
                            g_r[(size_t)rowg * CH + col] = acc[r];
                        }
                    }
                }
            }
        }
    }
}

// ---------------------------------------------------------------------------
// One wave per node, quarter-wave (16 lanes x 8 ch) per edge, 4 edges/group.
// V2: ALL <=48 records of the bucket are preloaded in ONE coalesced 4B/lane
// load; per-group records come from a register via one shfl. This removes
// the per-iteration rec-load -> gather dependent chain, so the g_l gathers can
// be pipelined depth-3 (covers ~600cy L3 gather latency with ~200cy/group
// compute).
__global__ __launch_bounds__(256) void node_attn_kernel(
    const uint4* __restrict__ g_lb4, const float* __restrict__ g_r,
    const float* __restrict__ attn_w,
    const unsigned* __restrict__ recs, const int* __restrict__ counts,
    float* __restrict__ out)
{
    int gid = blockIdx.x * blockDim.x + threadIdx.x;
    int wid = gid >> 6;
    if (wid >= N_NODES) return;
    const int lane = threadIdx.x & 63;
    const int q4 = lane >> 4;    // quarter 0..3: which edge of the group of 4
    const int sl = lane & 15;    // sub-lane: channels sl*8 .. sl*8+7

    int cnt = counts[wid];
    if (cnt > CAP) cnt = CAP;

    float gr[8], aw[8];
    {
        const float4* grp = (const float4*)(g_r + (size_t)wid * CH + sl * 8);
        float4 a = grp[0], b = grp[1];
        gr[0] = a.x; gr[1] = a.y; gr[2] = a.z; gr[3] = a.w;
        gr[4] = b.x; gr[5] = b.y; gr[6] = b.z; gr[7] = b.w;
        const float4* awp = (const float4*)(attn_w + sl * 8);
        float4 c = awp[0], d = awp[1];
        aw[0] = c.x; aw[1] = c.y; aw[2] = c.z; aw[3] = c.w;
        aw[4] = d.x; aw[5] = d.y; aw[6] = d.z; aw[7] = d.w;
    }

    float l = 0.0f;
    float acc[8] = {0.f, 0.f, 0.f, 0.f, 0.f, 0.f, 0.f, 0.f};

    if (cnt > 0) {
        const int clampi = cnt - 1;
        // whole bucket in one coalesced load (lanes >= cnt clamp to last slot)
        unsigned rcl = recs[wid * CAP + min(lane, clampi)];
        const int G = (cnt + 3) >> 2;   // groups of 4 edges

        #define REC_OF(jg, rv) { int e_ = (jg) * 4 + q4; if (e_ > clampi) e_ = clampi; \
                                 rv = __shfl(rcl, e_, 64); }

        unsigned r0, r1, r2, r3;
        uint4 gA, gB, gC, gD;
        REC_OF(0, r0); gA = g_lb4[(size_t)(r0 & 0xFFFFu) * (CH / 8) + sl];
        r1 = r0; r2 = r0; gB = gA; gC = gA;
        if (G > 1) { REC_OF(1, r1); gB = g_lb4[(size_t)(r1 & 0xFFFFu) * (CH / 8) + sl]; }
        if (G > 2) { REC_OF(2, r2); gC = g_lb4[(size_t)(r2 & 0xFFFFu) * (CH / 8) + sl]; }

        for (int j = 0; j < G; ++j) {
            r3 = r0; gD = gA;                 // init so tail rotation is defined
            if (j + 3 < G) {                  // wave-uniform branch
                REC_OF(j + 3, r3);
                gD = g_lb4[(size_t)(r3 & 0xFFFFu) * (CH / 8) + sl];
            }

            bool active = (j * 4 + q4) < cnt;
            float ev = __uint_as_float(r0 & 0xFFFF0000u);

            float gl[8];
            gl[0] = __uint_as_float(gA.x << 16);
            gl[1] = __uint_as_float(gA.x & 0xFFFF0000u);
            gl[2] = __uint_as_float(gA.y << 16);
            gl[3] = __uint_as_float(gA.y & 0xFFFF0000u);
            gl[4] = __uint_as_float(gA.z << 16);
            gl[5] = __uint_as_float(gA.z & 0xFFFF0000u);
            gl[6] = __uint_as_float(gA.w << 16);
            gl[7] = __uint_as_float(gA.w & 0xFFFF0000u);

            float p = 0.0f;
            #pragma unroll
            for (int c = 0; c < 8; ++c) {
                float h = gl[c] + gr[c];
                float sg = __builtin_amdgcn_rcpf(1.0f + __expf(-h));  // sigmoid
                p = fmaf(h * aw[c], sg, p);                            // silu*aw
            }
            p += __shfl_xor(p, 1, 64);
            p += __shfl_xor(p, 2, 64);
            p += __shfl_xor(p, 4, 64);
            p += __shfl_xor(p, 8, 64);

            float w = __expf(p) * (active ? ev : 0.0f);  // = exp(p+log(env))
            l += w;
            #pragma unroll
            for (int c = 0; c < 8; ++c) acc[c] = fmaf(w, gl[c], acc[c]);

            r0 = r1; gA = gB; r1 = r2; gB = gC; r2 = r3; gC = gD;
        }
        #undef REC_OF
    }

    #pragma unroll
    for (int o = 16; o <= 32; o <<= 1) {
        l += __shfl_xor(l, o, 64);
        #pragma unroll
        for (int c = 0; c < 8; ++c) acc[c] += __shfl_xor(acc[c], o, 64);
    }

    if (q4 == 0) {
        float inv = (l > 0.0f) ? __builtin_amdgcn_rcpf(l) : 0.0f;
        float4 o0 = {acc[0] * inv, acc[1] * inv, acc[2] * inv, acc[3] * inv};
        float4 o1 = {acc[4] * inv, acc[5] * inv, acc[6] * inv, acc[7] * inv};
        float4* op = (float4*)(out + (size_t)wid * CH + sl * 8);
        op[0] = o0;
        op[1] = o1;
    }
}

// ---------------------------------------------------------------------------
extern "C" void kernel_launch(void* const* d_in, const int* in_sizes, int n_in,
                              void* d_out, int out_size, void* d_ws, size_t ws_size,
                              hipStream_t stream)
{
    const float* q      = (const float*)d_in[0];
    // d_in[1]=k, d_in[2]=v : unused (matches reference)
    const float* env    = (const float*)d_in[3];
    const float* W_l    = (const float*)d_in[4];
    const float* W_r    = (const float*)d_in[5];
    const float* attn_w = (const float*)d_in[6];
    const int*   eidx   = (const int*)d_in[7];
    const int* src = eidx;
    const int* dst = eidx + N_EDGES;
    float* out = (float*)d_out;

    float* ws    = (float*)d_ws;
    unsigned* g_lb = (unsigned*)ws;                      // N*CH/2 uints (bf16 pairs)
    float* g_r   = (float*)(g_lb + (size_t)N_NODES * (CH / 2));  // N*CH fp32
    uint4* Wf4   = (uint4*)(g_r + (size_t)N_NODES * CH); // 4096 uint4 = 64 KB
    unsigned* recs = (unsigned*)(Wf4 + 4096);            // N*CAP 4B records (9.6 MB)
    int* counts  = (int*)(recs + (size_t)N_NODES * CAP); // N

    prep_pack_kernel<<<64, 256, 0, stream>>>(W_l, W_r, Wf4, counts);

    fused_scatter_gemm_kernel<<<TOTAL_BLOCKS, 256, 0, stream>>>(
        src, dst, env, counts, recs, q, Wf4, (unsigned short*)g_lb, g_r);

    int node_wave_blocks = (N_NODES * 64 + 255) / 256;
    node_attn_kernel<<<node_wave_blocks, 256, 0, stream>>>(
        (const uint4*)g_lb, g_r, attn_w, recs, counts, out);
}

// Round 4
// 227.928 us; speedup vs baseline: 1.0251x; 1.0058x over previous
//
#include <hip/hip_runtime.h>
#include <math.h>

#define N_NODES 50000
#define N_EDGES 800000
#define CH 128
#define NXCD 8
#define CAPX 16  // slots per (node, xcd); per-XCD deg ~ Poisson(2), P(>=16) ~ 5e-10
#define SCAT_BLOCKS ((N_EDGES + 255) / 256)   // 3125
#define GEMM_BLOCKS ((N_NODES + 63) / 64)     // 782
#define TOTAL_BLOCKS (SCAT_BLOCKS + GEMM_BLOCKS)  // 3907

typedef __attribute__((ext_vector_type(8))) short short8;
typedef __attribute__((ext_vector_type(4))) float f32x4;
union FragU { uint4 u; short8 s; };

// RNE-pack two fp32 into (lo,hi) bf16 halves of a uint.
__device__ __forceinline__ unsigned pack_bf16(float a, float b) {
    unsigned ua = __float_as_uint(a);
    unsigned ub = __float_as_uint(b);
    ua += 0x7FFFu + ((ua >> 16) & 1u);
    ub += 0x7FFFu + ((ub >> 16) & 1u);
    return (ua >> 16) | (ub & 0xFFFF0000u);
}

// ---------------------------------------------------------------------------
// prep_pack: swizzle W_l,W_r (fp32 [out][in]) into MFMA B-fragment-ordered
// bf16 (layout proven round 7). Also zeroes the 8-shard counts array.
__global__ __launch_bounds__(256) void prep_pack_kernel(
    const float* __restrict__ W_l, const float* __restrict__ W_r,
    uint4* __restrict__ Wf4, unsigned* __restrict__ counts)
{
    int tid = blockIdx.x * 256 + threadIdx.x;   // grid 64 blocks -> 16384 threads
    if (tid < 2 * 8 * 4 * 64) {
        int lane  = tid & 63;
        int chunk = (tid >> 6) & 3;
        int tile  = (tid >> 8) & 7;
        int mat   = tid >> 11;
        const float* W = mat ? W_r : W_l;
        int n  = tile * 16 + (lane & 15);
        int k0 = chunk * 32 + (lane >> 4) * 8;
        const float* wp = W + n * CH + k0;
        float4 a = *(const float4*)wp;
        float4 b = *(const float4*)(wp + 4);
        uint4 p;
        p.x = pack_bf16(a.x, a.y);
        p.y = pack_bf16(a.z, a.w);
        p.z = pack_bf16(b.x, b.y);
        p.w = pack_bf16(b.z, b.w);
        Wf4[tid] = p;
    }
    for (int i = tid; i < NXCD * N_NODES; i += 64 * 256) counts[i] = 0;
}

// ---------------------------------------------------------------------------
// Fused scatter + GEMM, round-0 block order (scatter first, GEMM appended —
// round-3 post-mortem: striping GEMM into the scatter residency window costs
// ~3 us + 4 MB extra writebacks from L2 interference; appended is better).
//
// Scatter V3: XCD-SHARDED counters + records.
//   Device-scope atomicAdd executes past L2 at the fabric coherence point:
//   800k of them = the ~70 us wall (4.8/cycle device-wide). Each block reads
//   its physical XCD id (HW_REG_XCC_ID, m09) and uses counts[xcc][node] +
//   recs[xcc][node][CAPX]. Only one XCD ever touches a given word, so
//   WORKGROUP-scope atomicity (RMW in the local XCD L2, no cross-XCD
//   obligation) suffices -> ~200cy L2 atomics instead of fabric round trips.
//   Shard regions are 64B-line-disjoint (CAPX=16 -> one line per (node,xcd))
//   so non-coherent L2 writebacks cannot clobber across shards, and each
//   XCD's 3.2 MB shard fits its own 4 MB L2 -> recs write churn gone.
// NOTE (round-2): no nontemporal stores — intermediates must stay in cache.
__global__ __launch_bounds__(256) void fused_scatter_gemm_kernel(
    const int* __restrict__ src, const int* __restrict__ dst,
    const float* __restrict__ env,
    unsigned* __restrict__ counts, unsigned* __restrict__ recs,
    const float* __restrict__ q, const uint4* __restrict__ Wf4,
    unsigned short* __restrict__ g_l16, float* __restrict__ g_r)
{
    const int b = blockIdx.x;
    if (b < SCAT_BLOCKS) {
        int i = b * 256 + threadIdx.x;
        if (i < N_EDGES) {
            unsigned xcc;
            asm("s_getreg_b32 %0, hwreg(HW_REG_XCC_ID)" : "=s"(xcc));
            xcc &= 7;
            int d  = dst[i];
            int sv = src[i];
            float evf = env[i] + 1e-7f;
            unsigned* cp = &counts[xcc * N_NODES + d];
            unsigned rank = __hip_atomic_fetch_add(cp, 1u, __ATOMIC_RELAXED,
                                                   __HIP_MEMORY_SCOPE_WORKGROUP);
            if (rank < CAPX) {
                unsigned ev = __float_as_uint(evf);
                ev += 0x7FFFu + ((ev >> 16) & 1u);     // RNE to bf16
                recs[((size_t)(xcc * N_NODES + d) << 4) + rank] =
                    (unsigned)sv | (ev & 0xFFFF0000u);
            }
        }
    } else {
        // ---- MFMA GEMM: g_l(bf16) = q@W_l^T, g_r(fp32) = q@W_r^T
        // layouts [m89/m91]: A/B lane idx = lane&15; C/D col=lane&15,
        // row=(lane>>4)*4+reg.
        const int g    = b - SCAT_BLOCKS;
        const int wv   = threadIdx.x >> 6;
        const int lane = threadIdx.x & 63;
        const int m    = lane & 15;
        const int quad = lane >> 4;
        const int row0 = g * 64 + wv * 16;

        int arow = row0 + m;
        if (arow >= N_NODES) arow = N_NODES - 1;   // clamp (stores guarded)
        const float* qr = q + (size_t)arow * CH + quad * 8;

        FragU A[4];
        #pragma unroll
        for (int c = 0; c < 4; ++c) {
            float4 x = *(const float4*)(qr + c * 32);
            float4 y = *(const float4*)(qr + c * 32 + 4);
            A[c].u.x = pack_bf16(x.x, x.y);
            A[c].u.y = pack_bf16(x.z, x.w);
            A[c].u.z = pack_bf16(y.x, y.y);
            A[c].u.w = pack_bf16(y.z, y.w);
        }

        for (int mat = 0; mat < 2; ++mat) {
            for (int tile = 0; tile < 8; ++tile) {
                f32x4 acc = {0.f, 0.f, 0.f, 0.f};
                const uint4* bp = Wf4 + (size_t)((mat * 8 + tile) * 4) * 64 + lane;
                #pragma unroll
                for (int c = 0; c < 4; ++c) {
                    FragU B; B.u = bp[c * 64];
                    acc = __builtin_amdgcn_mfma_f32_16x16x32_bf16(A[c].s, B.s, acc, 0, 0, 0);
                }
                int col = tile * 16 + m;
                #pragma unroll
                for (int r = 0; r < 4; ++r) {
                    int rowg = row0 + quad * 4 + r;
                    if (rowg < N_NODES) {
                        if (mat == 0) {
                            unsigned u = __float_as_uint(acc[r]);
                            u += 0x7FFFu + ((u >> 16) & 1u);
                            g_l16[(size_t)rowg * CH + col] = (unsigned short)(u >> 16);
                        } else {
                            g_r[(size_t)rowg * CH + col] = acc[r];
                        }
                    }
                }
            }
        }
    }
}

// ---------------------------------------------------------------------------
// One wave per node, quarter-wave (16 lanes x 8 ch) per edge, 4 edges/group.
// Records now live in 8 XCD shards; the wave sums the 8 per-shard counts,
// maps concatenated index -> (shard, offset) with a 7-step register walk, and
// preloads the whole logical bucket (<=64 records) one 4B load per lane.
// Per-group records come from registers via shfl; g_l gathers pipelined
// depth-3. Group order differs from arrival order — segment sums are
// order-independent within tolerance.
__global__ __launch_bounds__(256) void node_attn_kernel(
    const uint4* __restrict__ g_lb4, const float* __restrict__ g_r,
    const float* __restrict__ attn_w,
    const unsigned* __restrict__ recs, const unsigned* __restrict__ counts,
    float* __restrict__ out)
{
    int gid = blockIdx.x * blockDim.x + threadIdx.x;
    int wid = gid >> 6;
    if (wid >= N_NODES) return;
    const int lane = threadIdx.x & 63;
    const int q4 = lane >> 4;    // quarter 0..3: which edge of the group of 4
    const int sl = lane & 15;    // sub-lane: channels sl*8 .. sl*8+7

    // per-shard counts -> total
    unsigned cx = 0;
    if (lane < NXCD) {
        cx = counts[lane * N_NODES + wid];
        if (cx > CAPX) cx = CAPX;
    }
    unsigned tot = cx;
    tot += __shfl_xor(tot, 1, 64);
    tot += __shfl_xor(tot, 2, 64);
    tot += __shfl_xor(tot, 4, 64);
    int cnt = (int)__shfl(tot, 0, 64);
    if (cnt > 64) cnt = 64;      // wave preload capacity (deg>64 ~ never)

    float gr[8], aw[8];
    {
        const float4* grp = (const float4*)(g_r + (size_t)wid * CH + sl * 8);
        float4 a = grp[0], b = grp[1];
        gr[0] = a.x; gr[1] = a.y; gr[2] = a.z; gr[3] = a.w;
        gr[4] = b.x; gr[5] = b.y; gr[6] = b.z; gr[7] = b.w;
        const float4* awp = (const float4*)(attn_w + sl * 8);
        float4 c = awp[0], d = awp[1];
        aw[0] = c.x; aw[1] = c.y; aw[2] = c.z; aw[3] = c.w;
        aw[4] = d.x; aw[5] = d.y; aw[6] = d.z; aw[7] = d.w;
    }

    float l = 0.0f;
    float acc[8] = {0.f, 0.f, 0.f, 0.f, 0.f, 0.f, 0.f, 0.f};

    if (cnt > 0) {
        const int clampi = cnt - 1;
        // map concatenated index min(lane,cnt-1) -> (shard sh, offset rrem)
        int rrem = min(lane, clampi);
        int sh = 0;
        #pragma unroll
        for (int x = 0; x < NXCD - 1; ++x) {
            int cxx = (int)__shfl(cx, x, 64);
            if (sh == x && rrem >= cxx) { rrem -= cxx; sh = x + 1; }
        }
        unsigned rcl = recs[((size_t)(sh * N_NODES + wid) << 4) + rrem];
        const int G = (cnt + 3) >> 2;   // groups of 4 edges

        #define REC_OF(jg, rv) { int e_ = (jg) * 4 + q4; if (e_ > clampi) e_ = clampi; \
                                 rv = __shfl(rcl, e_, 64); }

        unsigned r0, r1, r2, r3;
        uint4 gA, gB, gC, gD;
        REC_OF(0, r0); gA = g_lb4[(size_t)(r0 & 0xFFFFu) * (CH / 8) + sl];
        r1 = r0; r2 = r0; gB = gA; gC = gA;
        if (G > 1) { REC_OF(1, r1); gB = g_lb4[(size_t)(r1 & 0xFFFFu) * (CH / 8) + sl]; }
        if (G > 2) { REC_OF(2, r2); gC = g_lb4[(size_t)(r2 & 0xFFFFu) * (CH / 8) + sl]; }

        for (int j = 0; j < G; ++j) {
            r3 = r0; gD = gA;                 // init so tail rotation is defined
            if (j + 3 < G) {                  // wave-uniform branch
                REC_OF(j + 3, r3);
                gD = g_lb4[(size_t)(r3 & 0xFFFFu) * (CH / 8) + sl];
            }

            bool active = (j * 4 + q4) < cnt;
            float ev = __uint_as_float(r0 & 0xFFFF0000u);

            float gl[8];
            gl[0] = __uint_as_float(gA.x << 16);
            gl[1] = __uint_as_float(gA.x & 0xFFFF0000u);
            gl[2] = __uint_as_float(gA.y << 16);
            gl[3] = __uint_as_float(gA.y & 0xFFFF0000u);
            gl[4] = __uint_as_float(gA.z << 16);
            gl[5] = __uint_as_float(gA.z & 0xFFFF0000u);
            gl[6] = __uint_as_float(gA.w << 16);
            gl[7] = __uint_as_float(gA.w & 0xFFFF0000u);

            float p = 0.0f;
            #pragma unroll
            for (int c = 0; c < 8; ++c) {
                float h = gl[c] + gr[c];
                float sg = __builtin_amdgcn_rcpf(1.0f + __expf(-h));  // sigmoid
                p = fmaf(h * aw[c], sg, p);                            // silu*aw
            }
            p += __shfl_xor(p, 1, 64);
            p += __shfl_xor(p, 2, 64);
            p += __shfl_xor(p, 4, 64);
            p += __shfl_xor(p, 8, 64);

            float w = __expf(p) * (active ? ev : 0.0f);  // = exp(p+log(env))
            l += w;
            #pragma unroll
            for (int c = 0; c < 8; ++c) acc[c] = fmaf(w, gl[c], acc[c]);

            r0 = r1; gA = gB; r1 = r2; gB = gC; r2 = r3; gC = gD;
        }
        #undef REC_OF
    }

    #pragma unroll
    for (int o = 16; o <= 32; o <<= 1) {
        l += __shfl_xor(l, o, 64);
        #pragma unroll
        for (int c = 0; c < 8; ++c) acc[c] += __shfl_xor(acc[c], o, 64);
    }

    if (q4 == 0) {
        float inv = (l > 0.0f) ? __builtin_amdgcn_rcpf(l) : 0.0f;
        float4 o0 = {acc[0] * inv, acc[1] * inv, acc[2] * inv, acc[3] * inv};
        float4 o1 = {acc[4] * inv, acc[5] * inv, acc[6] * inv, acc[7] * inv};
        float4* op = (float4*)(out + (size_t)wid * CH + sl * 8);
        op[0] = o0;
        op[1] = o1;
    }
}

// ---------------------------------------------------------------------------
extern "C" void kernel_launch(void* const* d_in, const int* in_sizes, int n_in,
                              void* d_out, int out_size, void* d_ws, size_t ws_size,
                              hipStream_t stream)
{
    const float* q      = (const float*)d_in[0];
    // d_in[1]=k, d_in[2]=v : unused (matches reference)
    const float* env    = (const float*)d_in[3];
    const float* W_l    = (const float*)d_in[4];
    const float* W_r    = (const float*)d_in[5];
    const float* attn_w = (const float*)d_in[6];
    const int*   eidx   = (const int*)d_in[7];
    const int* src = eidx;
    const int* dst = eidx + N_EDGES;
    float* out = (float*)d_out;

    float* ws    = (float*)d_ws;
    unsigned* g_lb = (unsigned*)ws;                      // N*CH/2 uints (bf16 pairs) 12.8MB
    float* g_r   = (float*)(g_lb + (size_t)N_NODES * (CH / 2));  // N*CH fp32 25.6MB
    uint4* Wf4   = (uint4*)(g_r + (size_t)N_NODES * CH); // 4096 uint4 = 64 KB
    unsigned* recs = (unsigned*)(Wf4 + 4096);            // 8*N*CAPX 4B records (25.6MB)
    unsigned* counts = recs + (size_t)NXCD * N_NODES * CAPX; // 8*N (1.6MB)

    prep_pack_kernel<<<64, 256, 0, stream>>>(W_l, W_r, Wf4, counts);

    fused_scatter_gemm_kernel<<<TOTAL_BLOCKS, 256, 0, stream>>>(
        src, dst, env, counts, recs, q, Wf4, (unsigned short*)g_lb, g_r);

    int node_wave_blocks = (N_NODES * 64 + 255) / 256;
    node_attn_kernel<<<node_wave_blocks, 256, 0, stream>>>(
        (const uint4*)g_lb, g_r, attn_w, recs, counts, out);
}

// Round 5
// 224.884 us; speedup vs baseline: 1.0389x; 1.0135x over previous
//
#include <hip/hip_runtime.h>
#include <math.h>

#define N_NODES 50000
#define N_EDGES 800000
#define CH 128
#define CAP 48   // slots per node; deg ~ Poisson(16), P(deg>=48) ~ 1e-10
#define SCAT_BLOCKS ((N_EDGES + 255) / 256)    // 3125
#define GEMM_BLOCKS ((N_NODES + 127) / 128)    // 391 (128 rows/block, 512 thr)

typedef __attribute__((ext_vector_type(8))) short short8;
typedef __attribute__((ext_vector_type(4))) float f32x4;
union FragU { uint4 u; short8 s; };

// RNE-pack two fp32 into (lo,hi) bf16 halves of a uint.
__device__ __forceinline__ unsigned pack_bf16(float a, float b) {
    unsigned ua = __float_as_uint(a);
    unsigned ub = __float_as_uint(b);
    ua += 0x7FFFu + ((ua >> 16) & 1u);
    ub += 0x7FFFu + ((ub >> 16) & 1u);
    return (ua >> 16) | (ub & 0xFFFF0000u);
}

// ---------------------------------------------------------------------------
// prep_pack: swizzle W_l,W_r (fp32 [out][in]) into MFMA B-fragment-ordered
// bf16 (layout proven round 7). Also zeroes counts (folds the memset dispatch).
__global__ __launch_bounds__(256) void prep_pack_kernel(
    const float* __restrict__ W_l, const float* __restrict__ W_r,
    uint4* __restrict__ Wf4, int* __restrict__ counts)
{
    int tid = blockIdx.x * 256 + threadIdx.x;   // grid 64 blocks -> 16384 threads
    if (tid < 2 * 8 * 4 * 64) {
        int lane  = tid & 63;
        int chunk = (tid >> 6) & 3;
        int tile  = (tid >> 8) & 7;
        int mat   = tid >> 11;
        const float* W = mat ? W_r : W_l;
        int n  = tile * 16 + (lane & 15);
        int k0 = chunk * 32 + (lane >> 4) * 8;
        const float* wp = W + n * CH + k0;
        float4 a = *(const float4*)wp;
        float4 b = *(const float4*)(wp + 4);
        uint4 p;
        p.x = pack_bf16(a.x, a.y);
        p.y = pack_bf16(a.z, a.w);
        p.z = pack_bf16(b.x, b.y);
        p.w = pack_bf16(b.z, b.w);
        Wf4[tid] = p;
    }
    for (int i = tid; i < N_NODES; i += 64 * 256) counts[i] = 0;
}

// ---------------------------------------------------------------------------
// Scatter only (split from GEMM for per-phase visibility — rounds 0-4 showed
// the fused kernel pinned at ~70us under FOUR different scatter designs;
// device atomics, nt, striping, XCD-sharded L2 atomics all equal. Simplest
// form retained: device-scope atomicAdd + single cap-slot record array).
__global__ __launch_bounds__(256) void scatter_kernel(
    const int* __restrict__ src, const int* __restrict__ dst,
    const float* __restrict__ env,
    int* __restrict__ counts, unsigned* __restrict__ recs)
{
    int i = blockIdx.x * 256 + threadIdx.x;
    if (i < N_EDGES) {
        int d = dst[i];
        int rank = atomicAdd(&counts[d], 1);
        if (rank < CAP) {
            unsigned ev = __float_as_uint(env[i] + 1e-7f);
            ev += 0x7FFFu + ((ev >> 16) & 1u);     // RNE to bf16
            recs[d * CAP + rank] = (unsigned)src[i] | (ev & 0xFFFF0000u);
        }
    }
}

// ---------------------------------------------------------------------------
// MFMA GEMM: g_l(bf16) = q@W_l^T, g_r(fp32) = q@W_r^T.
// layouts [m89/m91]: A/B lane idx = lane&15; C/D col=lane&15, row=(lane>>4)*4+reg.
// V2: Wf4 (64 KB) staged in LDS once per block — the previous version
// re-read 1 KB/thread of B-fragments from L2 (~200 MB L2->reg, 64x ~200cy
// round trips per wave); ds_read_b128 is ~12cy and conflict-free (contiguous
// 16B/lane). 512 threads / 128 rows per block; 2 blocks/CU at 64 KB LDS.
__global__ __launch_bounds__(512) void gemm_kernel(
    const float* __restrict__ q, const uint4* __restrict__ Wf4,
    unsigned short* __restrict__ g_l16, float* __restrict__ g_r)
{
    __shared__ uint4 sW[4096];   // 64 KB: both matrices, fragment-ordered
    for (int i = threadIdx.x; i < 4096; i += 512) sW[i] = Wf4[i];

    const int wv   = threadIdx.x >> 6;      // 0..7
    const int lane = threadIdx.x & 63;
    const int m    = lane & 15;
    const int quad = lane >> 4;
    const int row0 = blockIdx.x * 128 + wv * 16;

    int arow = row0 + m;
    if (arow >= N_NODES) arow = N_NODES - 1;   // clamp (stores guarded)
    const float* qr = q + (size_t)arow * CH + quad * 8;

    FragU A[4];
    #pragma unroll
    for (int c = 0; c < 4; ++c) {
        float4 x = *(const float4*)(qr + c * 32);
        float4 y = *(const float4*)(qr + c * 32 + 4);
        A[c].u.x = pack_bf16(x.x, x.y);
        A[c].u.y = pack_bf16(x.z, x.w);
        A[c].u.z = pack_bf16(y.x, y.y);
        A[c].u.w = pack_bf16(y.z, y.w);
    }

    __syncthreads();

    for (int mat = 0; mat < 2; ++mat) {
        for (int tile = 0; tile < 8; ++tile) {
            f32x4 acc = {0.f, 0.f, 0.f, 0.f};
            const uint4* bp = sW + (size_t)(mat * 8 + tile) * 256;
            #pragma unroll
            for (int c = 0; c < 4; ++c) {
                FragU B; B.u = bp[c * 64 + lane];
                acc = __builtin_amdgcn_mfma_f32_16x16x32_bf16(A[c].s, B.s, acc, 0, 0, 0);
            }
            int col = tile * 16 + m;
            #pragma unroll
            for (int r = 0; r < 4; ++r) {
                int rowg = row0 + quad * 4 + r;
                if (rowg < N_NODES) {
                    if (mat == 0) {
                        unsigned u = __float_as_uint(acc[r]);
                        u += 0x7FFFu + ((u >> 16) & 1u);
                        g_l16[(size_t)rowg * CH + col] = (unsigned short)(u >> 16);
                    } else {
                        g_r[(size_t)rowg * CH + col] = acc[r];
                    }
                }
            }
        }
    }
}

// ---------------------------------------------------------------------------
// One wave per node, quarter-wave (16 lanes x 8 ch) per edge, 4 edges/group.
// Whole <=48-record bucket preloaded in ONE coalesced 4B/lane load; per-group
// records from registers via shfl; g_l gathers pipelined depth-3.
__global__ __launch_bounds__(256) void node_attn_kernel(
    const uint4* __restrict__ g_lb4, const float* __restrict__ g_r,
    const float* __restrict__ attn_w,
    const unsigned* __restrict__ recs, const int* __restrict__ counts,
    float* __restrict__ out)
{
    int gid = blockIdx.x * blockDim.x + threadIdx.x;
    int wid = gid >> 6;
    if (wid >= N_NODES) return;
    const int lane = threadIdx.x & 63;
    const int q4 = lane >> 4;    // quarter 0..3: which edge of the group of 4
    const int sl = lane & 15;    // sub-lane: channels sl*8 .. sl*8+7

    int cnt = counts[wid];
    if (cnt > CAP) cnt = CAP;

    float gr[8], aw[8];
    {
        const float4* grp = (const float4*)(g_r + (size_t)wid * CH + sl * 8);
        float4 a = grp[0], b = grp[1];
        gr[0] = a.x; gr[1] = a.y; gr[2] = a.z; gr[3] = a.w;
        gr[4] = b.x; gr[5] = b.y; gr[6] = b.z; gr[7] = b.w;
        const float4* awp = (const float4*)(attn_w + sl * 8);
        float4 c = awp[0], d = awp[1];
        aw[0] = c.x; aw[1] = c.y; aw[2] = c.z; aw[3] = c.w;
        aw[4] = d.x; aw[5] = d.y; aw[6] = d.z; aw[7] = d.w;
    }

    float l = 0.0f;
    float acc[8] = {0.f, 0.f, 0.f, 0.f, 0.f, 0.f, 0.f, 0.f};

    if (cnt > 0) {
        const int clampi = cnt - 1;
        // whole bucket in one coalesced load (lanes >= cnt clamp to last slot)
        unsigned rcl = recs[wid * CAP + min(lane, clampi)];
        const int G = (cnt + 3) >> 2;   // groups of 4 edges

        #define REC_OF(jg, rv) { int e_ = (jg) * 4 + q4; if (e_ > clampi) e_ = clampi; \
                                 rv = __shfl(rcl, e_, 64); }

        unsigned r0, r1, r2, r3;
        uint4 gA, gB, gC, gD;
        REC_OF(0, r0); gA = g_lb4[(size_t)(r0 & 0xFFFFu) * (CH / 8) + sl];
        r1 = r0; r2 = r0; gB = gA; gC = gA;
        if (G > 1) { REC_OF(1, r1); gB = g_lb4[(size_t)(r1 & 0xFFFFu) * (CH / 8) + sl]; }
        if (G > 2) { REC_OF(2, r2); gC = g_lb4[(size_t)(r2 & 0xFFFFu) * (CH / 8) + sl]; }

        for (int j = 0; j < G; ++j) {
            r3 = r0; gD = gA;                 // init so tail rotation is defined
            if (j + 3 < G) {                  // wave-uniform branch
                REC_OF(j + 3, r3);
                gD = g_lb4[(size_t)(r3 & 0xFFFFu) * (CH / 8) + sl];
            }

            bool active = (j * 4 + q4) < cnt;
            float ev = __uint_as_float(r0 & 0xFFFF0000u);

            float gl[8];
            gl[0] = __uint_as_float(gA.x << 16);
            gl[1] = __uint_as_float(gA.x & 0xFFFF0000u);
            gl[2] = __uint_as_float(gA.y << 16);
            gl[3] = __uint_as_float(gA.y & 0xFFFF0000u);
            gl[4] = __uint_as_float(gA.z << 16);
            gl[5] = __uint_as_float(gA.z & 0xFFFF0000u);
            gl[6] = __uint_as_float(gA.w << 16);
            gl[7] = __uint_as_float(gA.w & 0xFFFF0000u);

            float p = 0.0f;
            #pragma unroll
            for (int c = 0; c < 8; ++c) {
                float h = gl[c] + gr[c];
                float sg = __builtin_amdgcn_rcpf(1.0f + __expf(-h));  // sigmoid
                p = fmaf(h * aw[c], sg, p);                            // silu*aw
            }
            p += __shfl_xor(p, 1, 64);
            p += __shfl_xor(p, 2, 64);
            p += __shfl_xor(p, 4, 64);
            p += __shfl_xor(p, 8, 64);

            float w = __expf(p) * (active ? ev : 0.0f);  // = exp(p+log(env))
            l += w;
            #pragma unroll
            for (int c = 0; c < 8; ++c) acc[c] = fmaf(w, gl[c], acc[c]);

            r0 = r1; gA = gB; r1 = r2; gB = gC; r2 = r3; gC = gD;
        }
        #undef REC_OF
    }

    #pragma unroll
    for (int o = 16; o <= 32; o <<= 1) {
        l += __shfl_xor(l, o, 64);
        #pragma unroll
        for (int c = 0; c < 8; ++c) acc[c] += __shfl_xor(acc[c], o, 64);
    }

    if (q4 == 0) {
        float inv = (l > 0.0f) ? __builtin_amdgcn_rcpf(l) : 0.0f;
        float4 o0 = {acc[0] * inv, acc[1] * inv, acc[2] * inv, acc[3] * inv};
        float4 o1 = {acc[4] * inv, acc[5] * inv, acc[6] * inv, acc[7] * inv};
        float4* op = (float4*)(out + (size_t)wid * CH + sl * 8);
        op[0] = o0;
        op[1] = o1;
    }
}

// ---------------------------------------------------------------------------
extern "C" void kernel_launch(void* const* d_in, const int* in_sizes, int n_in,
                              void* d_out, int out_size, void* d_ws, size_t ws_size,
                              hipStream_t stream)
{
    const float* q      = (const float*)d_in[0];
    // d_in[1]=k, d_in[2]=v : unused (matches reference)
    const float* env    = (const float*)d_in[3];
    const float* W_l    = (const float*)d_in[4];
    const float* W_r    = (const float*)d_in[5];
    const float* attn_w = (const float*)d_in[6];
    const int*   eidx   = (const int*)d_in[7];
    const int* src = eidx;
    const int* dst = eidx + N_EDGES;
    float* out = (float*)d_out;

    float* ws    = (float*)d_ws;
    unsigned* g_lb = (unsigned*)ws;                      // N*CH/2 uints (bf16 pairs)
    float* g_r   = (float*)(g_lb + (size_t)N_NODES * (CH / 2));  // N*CH fp32
    uint4* Wf4   = (uint4*)(g_r + (size_t)N_NODES * CH); // 4096 uint4 = 64 KB
    unsigned* recs = (unsigned*)(Wf4 + 4096);            // N*CAP 4B records (9.6 MB)
    int* counts  = (int*)(recs + (size_t)N_NODES * CAP); // N

    prep_pack_kernel<<<64, 256, 0, stream>>>(W_l, W_r, Wf4, counts);

    scatter_kernel<<<SCAT_BLOCKS, 256, 0, stream>>>(src, dst, env, counts, recs);

    gemm_kernel<<<GEMM_BLOCKS, 512, 0, stream>>>(
        q, Wf4, (unsigned short*)g_lb, g_r);

    int node_wave_blocks = (N_NODES * 64 + 255) / 256;
    node_attn_kernel<<<node_wave_blocks, 256, 0, stream>>>(
        (const uint4*)g_lb, g_r, attn_w, recs, counts, out);
}